// Round 9
// baseline (254.340 us; speedup 1.0000x reference)
//
#include <hip/hip_runtime.h>

// RingAttention: out = softmax(Q K^T) V (no scale), B=32 SQ=1024 SKV=8192 D=64, fp32 I/O.
// R15: real fix for R13/R14's absmax 0.578 (bit-identical -> deterministic math bug,
// NOT reassociation). Root cause: pk_exp2 clamped x at -14 -> P=2^-14 (6.1e-5) for all
// far-below-max scores instead of 0; ~2700 such keys/row/split inflate l by ~0.17/split
// -> output deflated 10-30% -> absmax ~0.578. v_exp_f32 (R12) underflowed these to 0.
// Fix: flush-to-zero mask r &= (x > -13) per packed lane; survivors have n >= -13 so
// the exponent-field add stays normal. Dropped true mass (band (-24,-13)) < 0.02 in l.
// R13 perf thesis still under test: v_exp_f32 quarter-rate was ~62% of tile time;
// packed-fp16 exp2 should cut ring_attn 132 -> ~105-115us if right.
// Guards: WRITE_SIZE 25344 KB (no spill); absmax < ~0.05.
// Carried: R12 fused subtract + defer-max THR=8, ones-MFMA accL; R11 NSPLIT=3 grid 768
// (3/CU, zero tail), same-XCD sharers, merge3; R8 (256,3), lgkmcnt-only barriers,
// 2-barrier tile, V-stage+prefetch under QK, max3 reduce, setprio, register prefetch,
// single-fp16 Q, permlane32_swap P exchange, conflict-free V^T staging, dbuf LDS,
// fp16 MFMA 32x32x16 S^T formulation.

#define NBATCH 32
#define SQL 1024
#define SKVL 8192
#define DH 64
#define BM 128                 // q rows per block (4 waves x 32)
#define BN 64                  // kv rows per tile
#define KSTR 72                // K lds row stride in halfs
#define VSTR 72                // V^T lds row stride in halfs
#define NSPL 3                 // splits per (batch,qb): grid 768 = 3 blocks/CU exactly
#define RESCALE_THR 8.0f       // defer-max threshold (fp16 P <= 2^8)

typedef _Float16 half8 __attribute__((ext_vector_type(8)));
typedef __fp16 fp16x2 __attribute__((ext_vector_type(2)));
typedef float floatx16 __attribute__((ext_vector_type(16)));
typedef float floatx4 __attribute__((ext_vector_type(4)));
typedef unsigned int uint4v __attribute__((ext_vector_type(4)));
typedef unsigned int uint2v __attribute__((ext_vector_type(2)));
typedef _Float16 h2v __attribute__((ext_vector_type(2)));
typedef unsigned short u16x2v __attribute__((ext_vector_type(2)));
typedef short s16x2v __attribute__((ext_vector_type(2)));

union F8U { uint4v u; half8 h; };

#if __has_builtin(__builtin_amdgcn_exp2f)
#define EXP2F(x) __builtin_amdgcn_exp2f(x)
#else
#define EXP2F(x) exp2f(x)
#endif

// __syncthreads minus the vmcnt drain: wait own LDS ops, barrier, fence reordering.
#define WGBAR() do {                                        \
    asm volatile("s_waitcnt lgkmcnt(0)" ::: "memory");      \
    __builtin_amdgcn_s_barrier();                           \
    asm volatile("" ::: "memory");                          \
  } while (0)

static __device__ __forceinline__ unsigned pk2(float a, float b) {
#if __has_builtin(__builtin_amdgcn_cvt_pkrtz)
  fp16x2 h = __builtin_amdgcn_cvt_pkrtz(a, b);
  return __builtin_bit_cast(unsigned, h);
#else
  union { _Float16 h[2]; unsigned u; } r;
  r.h[0] = (_Float16)a; r.h[1] = (_Float16)b; return r.u;
#endif
}

// packed exp2 on two fp16 values (full-rate VALU, no trans pipe).
// Magic round: y=x+1536 -> u16(y)=0x6600+round(x) (asm keeps y opaque vs fast-math).
// Cubic 2^f on [-0.5,0.5] (err ~6e-4); 2^n via exponent-field add.
// FLUSH: x <= -13 -> 0 (matches v_exp_f32 underflow semantics; R13/R14's 0.578 bug
// was returning 2^-14 here). Survivors have n >= -13 -> result always normal.
static __device__ __forceinline__ unsigned pk_exp2(unsigned xu) {
  const h2v CM14 = {(_Float16)-14.0f, (_Float16)-14.0f};
  const h2v CFL  = {(_Float16)-13.0f, (_Float16)-13.0f};
  const h2v CMAG = {(_Float16)1536.0f, (_Float16)1536.0f};
  const h2v C0 = {(_Float16)1.0f, (_Float16)1.0f};
  const h2v C1 = {(_Float16)0.6931472f, (_Float16)0.6931472f};
  const h2v C2 = {(_Float16)0.2402265f, (_Float16)0.2402265f};
  const h2v C3 = {(_Float16)0.0555041f, (_Float16)0.0555041f};
  h2v x = __builtin_bit_cast(h2v, xu);
  x = __builtin_elementwise_max(x, CM14);
  h2v y = x + CMAG;                        // u16(y) = 0x6600 + round(x)
  unsigned yu = __builtin_bit_cast(unsigned, y);
  asm("" : "+v"(yu));                      // opaque: forbid (x+1536)-1536 -> x folding
  y = __builtin_bit_cast(h2v, yu);
  h2v nf = y - CMAG;                       // n = round(x), exact
  h2v f  = x - nf;                         // f in [-0.5, 0.5]
  h2v p  = C2 + f * C3;                    // v_pk_fma_f16 chain
  p = C1 + f * p;
  p = C0 + f * p;                          // 2^f in [0.707, 1.414]
  u16x2v e = __builtin_bit_cast(u16x2v, y) - (u16x2v){0x6600, 0x6600};  // n
  e = e << 10;                             // n << 10 (exponent field)
  s16x2v kp = (x > CFL);                   // 0xFFFF keep / 0x0000 flush
  u16x2v r = (__builtin_bit_cast(u16x2v, p) + e) & __builtin_bit_cast(u16x2v, kp);
  return __builtin_bit_cast(unsigned, r);
}

#if __has_builtin(__builtin_amdgcn_permlane32_swap)
#define HAVE_PL32 1
static __device__ __forceinline__ void pl32(unsigned& a, unsigned& b) {
  uint2v r = __builtin_amdgcn_permlane32_swap(a, b, false, false);
  a = r[0]; b = r[1];
}
#else
#define HAVE_PL32 0
#endif

template<int NSPLIT>
__global__ __launch_bounds__(256, 3)
void ring_attn(const float* __restrict__ q, const float* __restrict__ k,
               const float* __restrict__ v, float* __restrict__ out,
               float* __restrict__ pO, float* __restrict__ pM, float* __restrict__ pL)
{
  constexpr int TT = SKVL / BN;            // 128 kv tiles total
  __shared__ _Float16 Kl[2][BN * KSTR];
  __shared__ _Float16 Vt[2][DH * VSTR];

  const int tid  = threadIdx.x;
  const int lane = tid & 63;
  const int wv   = tid >> 6;
  const int l31  = lane & 31;
  const int hb   = lane >> 5;
  const int b8   = hb * 8;

  int split, batch, qb;
  if (NSPLIT == 3) {                 // bi = qb*96 + batch*3 + split, grid 768
    split = blockIdx.x % 3;          // sharers of a K/V slice: bid stride 96 == same XCD
    batch = (blockIdx.x / 3) & 31;
    qb    = blockIdx.x / 96;         // 0..7
  } else {
    split = 0;
    batch = blockIdx.x & 31;
    qb    = blockIdx.x >> 5;
  }
  const int t0 = (split * TT) / NSPLIT;
  const int t1 = ((split + 1) * TT) / NSPLIT;

  const float* kp = k + (size_t)batch * SKVL * DH;
  const float* vp = v + (size_t)batch * SKVL * DH;

  // ---- Q: scale by log2(e), round to fp16 (B-operand frags: n=q=l31, k=d) ----
  const float* qp = q + ((size_t)batch * SQL + qb * BM + wv * 32 + l31) * DH;
  half8 qf[4];
#pragma unroll
  for (int kt = 0; kt < 4; ++kt) {
    float4 a = *(const float4*)(qp + kt * 16 + b8);
    float4 c = *(const float4*)(qp + kt * 16 + b8 + 4);
    float xs[8] = {a.x, a.y, a.z, a.w, c.x, c.y, c.z, c.w};
#pragma unroll
    for (int j = 0; j < 8; ++j)
      qf[kt][j] = (_Float16)(xs[j] * 1.44269504088896340736f);
  }

  // all-ones B operand for the row-sum (l) MFMA
  half8 ones;
#pragma unroll
  for (int j = 0; j < 8; ++j) ones[j] = (_Float16)1.0f;

  // K staging: thread -> row krt(+16*it), cols kc..kc+3 (fp32)
  const int krt = tid >> 4;
  const int kc  = (tid & 15) * 4;
  // V staging (n-major, conflict-free): thread -> rows vnr,vnr+1, cols vcg..vcg+7
  const int vnr = 2 * (tid & 31);
  const int vcg = 8 * (tid >> 5);

  float4 gk[4], ga0, ga1, gb0, gb1;
  {
    const float* kt_ = kp + (size_t)t0 * BN * DH;
    const float* vt_ = vp + (size_t)t0 * BN * DH;
#pragma unroll
    for (int it = 0; it < 4; ++it)
      gk[it] = *(const float4*)(kt_ + (size_t)(krt + it * 16) * DH + kc);
    ga0 = *(const float4*)(vt_ + (size_t)vnr * DH + vcg);
    ga1 = *(const float4*)(vt_ + (size_t)vnr * DH + vcg + 4);
    gb0 = *(const float4*)(vt_ + (size_t)(vnr + 1) * DH + vcg);
    gb1 = *(const float4*)(vt_ + (size_t)(vnr + 1) * DH + vcg + 4);
  }

  floatx16 accO[2], accL;
#pragma unroll
  for (int i = 0; i < 2; ++i)
#pragma unroll
    for (int r = 0; r < 16; ++r) accO[i][r] = 0.f;
#pragma unroll
  for (int r = 0; r < 16; ++r) accL[r] = 0.f;
  float m_run = 0.f;               // deferred running max (lane = q-row l31)

  int buf = 0;
  for (int tile = t0; tile < t1; ++tile) {
    _Float16* Kb = Kl[buf];
    _Float16* Vb = Vt[buf];

    // ---- stage K regs -> LDS[buf] ----
#pragma unroll
    for (int it = 0; it < 4; ++it) {
      uint2 w2 = make_uint2(pk2(gk[it].x, gk[it].y), pk2(gk[it].z, gk[it].w));
      *(uint2*)&Kb[(krt + it * 16) * KSTR + kc] = w2;
    }
    WGBAR();                         // B1: K visible; V loads still in flight

    // ---- stage V regs -> LDS[buf] (overlaps QK below) ----
    {
      float av[8] = {ga0.x, ga0.y, ga0.z, ga0.w, ga1.x, ga1.y, ga1.z, ga1.w};
      float bv[8] = {gb0.x, gb0.y, gb0.z, gb0.w, gb1.x, gb1.y, gb1.z, gb1.w};
#pragma unroll
      for (int i = 0; i < 8; ++i)
        *(unsigned*)&Vb[(vcg + i) * VSTR + vnr] = pk2(av[i], bv[i]);
    }

    // ---- issue next tile's loads ----
    if (tile + 1 < t1) {
      const float* kn = kp + (size_t)(tile + 1) * BN * DH;
      const float* vn = vp + (size_t)(tile + 1) * BN * DH;
#pragma unroll
      for (int it = 0; it < 4; ++it)
        gk[it] = *(const float4*)(kn + (size_t)(krt + it * 16) * DH + kc);
      ga0 = *(const float4*)(vn + (size_t)vnr * DH + vcg);
      ga1 = *(const float4*)(vn + (size_t)vnr * DH + vcg + 4);
      gb0 = *(const float4*)(vn + (size_t)(vnr + 1) * DH + vcg);
      gb1 = *(const float4*)(vn + (size_t)(vnr + 1) * DH + vcg + 4);
    }

    // ---- S' = K_tile · Q^T - m_run  (subtract fused via C-init) ----
    const float negm = -m_run;
    floatx16 st[2];
#pragma unroll
    for (int t = 0; t < 2; ++t)
#pragma unroll
      for (int r = 0; r < 16; ++r) st[t][r] = negm;
    __builtin_amdgcn_s_setprio(1);
#pragma unroll
    for (int kt = 0; kt < 4; ++kt) {
#pragma unroll
      for (int t = 0; t < 2; ++t) {
        half8 kf = *(const half8*)&Kb[(t * 32 + l31) * KSTR + kt * 16 + b8];
        st[t] = __builtin_amdgcn_mfma_f32_32x32x16_f16(kf, qf[kt], st[t], 0, 0, 0);
      }
    }
    __builtin_amdgcn_s_setprio(0);

    // ---- deferred online softmax: max check only; rare rescale path ----
    float mx;
    {
      float a[16];
#pragma unroll
      for (int r = 0; r < 16; ++r) a[r] = fmaxf(st[0][r], st[1][r]);
      float c0 = fmaxf(fmaxf(a[0],  a[1]),  fmaxf(a[2],  a[3]));
      float c1 = fmaxf(fmaxf(a[4],  a[5]),  fmaxf(a[6],  a[7]));
      float c2 = fmaxf(fmaxf(a[8],  a[9]),  fmaxf(a[10], a[11]));
      float c3 = fmaxf(fmaxf(a[12], a[13]), fmaxf(a[14], a[15]));
      mx = fmaxf(fmaxf(c0, c1), fmaxf(c2, c3));
    }
    mx = fmaxf(mx, __shfl_xor(mx, 32, 64));   // cross-half: full row max

    if (__any(mx > RESCALE_THR)) {            // rare: max grew meaningfully
      float d  = fmaxf(mx, 0.f);
      m_run += d;
      float al = EXP2F(-d);
#pragma unroll
      for (int t = 0; t < 2; ++t)
#pragma unroll
        for (int r = 0; r < 16; ++r) st[t][r] -= d;
#pragma unroll
      for (int r = 0; r < 16; ++r) {
        int row = (r & 3) + 8 * (r >> 2) + 4 * hb;
        float ar = __shfl(al, row, 64);
        accO[0][r] *= ar;
        accO[1][r] *= ar;
        accL[r]    *= ar;
      }
    }

    WGBAR();                         // B2: V^T visible; QK reads of Kb drained

    // ---- P = exp2(st) packed-fp16; P·V (+ row-sum into accL via ones MFMA) ----
    __builtin_amdgcn_s_setprio(1);
#pragma unroll
    for (int t = 0; t < 2; ++t) {
      unsigned P01 = pk_exp2(pk2(st[t][0],  st[t][1]));
      unsigned P23 = pk_exp2(pk2(st[t][2],  st[t][3]));
      unsigned P45 = pk_exp2(pk2(st[t][4],  st[t][5]));
      unsigned P67 = pk_exp2(pk2(st[t][6],  st[t][7]));
      unsigned P89 = pk_exp2(pk2(st[t][8],  st[t][9]));
      unsigned PAB = pk_exp2(pk2(st[t][10], st[t][11]));
      unsigned PCD = pk_exp2(pk2(st[t][12], st[t][13]));
      unsigned PEF = pk_exp2(pk2(st[t][14], st[t][15]));
      F8U fe, fo;
#if HAVE_PL32
      pl32(P01, P45); fe.u[0] = P01; fe.u[2] = P45;
      pl32(P23, P67); fe.u[1] = P23; fe.u[3] = P67;
      pl32(P89, PCD); fo.u[0] = P89; fo.u[2] = PCD;
      pl32(PAB, PEF); fo.u[1] = PAB; fo.u[3] = PEF;
#else
      unsigned x01 = __shfl_xor(P01, 32, 64), x23 = __shfl_xor(P23, 32, 64);
      unsigned x45 = __shfl_xor(P45, 32, 64), x67 = __shfl_xor(P67, 32, 64);
      unsigned x89 = __shfl_xor(P89, 32, 64), xAB = __shfl_xor(PAB, 32, 64);
      unsigned xCD = __shfl_xor(PCD, 32, 64), xEF = __shfl_xor(PEF, 32, 64);
      fe.u = uint4v{hb ? x45 : P01, hb ? x67 : P23, hb ? P45 : x01, hb ? P67 : x23};
      fo.u = uint4v{hb ? xCD : P89, hb ? xEF : PAB, hb ? PCD : x89, hb ? PEF : xAB};
#endif
      accL = __builtin_amdgcn_mfma_f32_32x32x16_f16(fe.h, ones, accL, 0, 0, 0);
      accL = __builtin_amdgcn_mfma_f32_32x32x16_f16(fo.h, ones, accL, 0, 0, 0);
#pragma unroll
      for (int ds = 0; ds < 2; ++ds) {
        half8 vf0 = *(const half8*)&Vb[(ds * 32 + l31) * VSTR + (2 * t) * 16 + b8];
        accO[ds] = __builtin_amdgcn_mfma_f32_32x32x16_f16(fe.h, vf0, accO[ds], 0, 0, 0);
        half8 vf1 = *(const half8*)&Vb[(ds * 32 + l31) * VSTR + (2 * t + 1) * 16 + b8];
        accO[ds] = __builtin_amdgcn_mfma_f32_32x32x16_f16(fo.h, vf1, accO[ds], 0, 0, 0);
      }
    }
    __builtin_amdgcn_s_setprio(0);
    buf ^= 1;
  }

  const int rowbase = batch * SQL + qb * BM + wv * 32;
  if (NSPLIT == 1) {
    float* op = out + (size_t)rowbase * DH;
#pragma unroll
    for (int r = 0; r < 16; ++r) {
      int row = (r & 3) + 8 * (r >> 2) + 4 * hb;
      float lr = 1.0f / accL[r];              // all lanes hold row sums
      op[(size_t)row * DH + l31]      = accO[0][r] * lr;
      op[(size_t)row * DH + 32 + l31] = accO[1][r] * lr;
    }
  } else {
    // unnormalized partials + (m,l) per q-row
    float* po = pO + ((size_t)split * NBATCH * SQL + rowbase) * DH;
#pragma unroll
    for (int r = 0; r < 16; ++r) {
      int row = (r & 3) + 8 * (r >> 2) + 4 * hb;
      po[(size_t)row * DH + l31]      = accO[0][r];
      po[(size_t)row * DH + 32 + l31] = accO[1][r];
    }
    if (hb == 0)
      pM[(size_t)split * NBATCH * SQL + rowbase + l31] = m_run;
    if (l31 == 0) {                           // lanes 0 and 32 cover all 32 rows
#pragma unroll
      for (int r = 0; r < 16; ++r) {
        int row = (r & 3) + 8 * (r >> 2) + 4 * hb;
        pL[(size_t)split * NBATCH * SQL + rowbase + row] = accL[r];
      }
    }
  }
}

__global__ __launch_bounds__(256)
void merge3(const float* __restrict__ pO, const float* __restrict__ pM,
            const float* __restrict__ pL, float* __restrict__ out)
{
  const int i4   = blockIdx.x * 256 + threadIdx.x;    // float4 index
  const int rowg = i4 >> 4;                           // (i4*4)>>6
  const size_t PLANE4 = (size_t)NBATCH * SQL * DH / 4;  // 524288
  const int    RPL    = NBATCH * SQL;                   // 32768
  float m0 = pM[rowg], m1 = pM[RPL + rowg], m2 = pM[2 * RPL + rowg];
  float mx = fmaxf(fmaxf(m0, m1), m2);
  float w0 = EXP2F(m0 - mx), w1 = EXP2F(m1 - mx), w2 = EXP2F(m2 - mx);
  float l = w0 * pL[rowg] + w1 * pL[RPL + rowg] + w2 * pL[2 * RPL + rowg];
  float li = 1.0f / l;
  const floatx4* p0 = (const floatx4*)pO;
  floatx4 o0 = p0[i4], o1 = p0[PLANE4 + i4], o2 = p0[2 * PLANE4 + i4];
  floatx4 o;
#pragma unroll
  for (int j = 0; j < 4; ++j)
    o[j] = (w0 * o0[j] + w1 * o1[j] + w2 * o2[j]) * li;
  ((floatx4*)out)[i4] = o;
}

extern "C" void kernel_launch(void* const* d_in, const int* in_sizes, int n_in,
                              void* d_out, int out_size, void* d_ws, size_t ws_size,
                              hipStream_t stream) {
  (void)in_sizes; (void)n_in; (void)out_size;
  const float* q = (const float*)d_in[0];
  const float* k = (const float*)d_in[1];
  const float* v = (const float*)d_in[2];
  float* out = (float*)d_out;

  const size_t PLANE = (size_t)NBATCH * SQL * DH;              // floats per split plane
  const size_t RPL   = (size_t)NBATCH * SQL;                   // rows per split
  const size_t need  = (3 * PLANE + 6 * RPL) * sizeof(float);  // ~26 MB

  if (ws_size >= need) {
    float* pO = (float*)d_ws;
    float* pM = pO + 3 * PLANE;
    float* pL = pM + 3 * RPL;
    ring_attn<NSPL><<<dim3(768), dim3(256), 0, stream>>>(q, k, v, nullptr, pO, pM, pL);
    merge3<<<dim3((NBATCH * SQL * DH) / 1024), dim3(256), 0, stream>>>(pO, pM, pL, out);
  } else {
    ring_attn<1><<<dim3(256), dim3(256), 0, stream>>>(q, k, v, out, nullptr, nullptr, nullptr);
  }
}

// Round 10
// 230.778 us; speedup vs baseline: 1.1021x; 1.1021x over previous
//
#include <hip/hip_runtime.h>

// RingAttention: out = softmax(Q K^T) V (no scale), B=32 SQ=1024 SKV=8192 D=64, fp32 I/O.
// R16: revert pk_exp2 (R15 proved it costs MORE VALU than quarter-rate v_exp_f32:
// VALUBusy 43->61.5, ring 132->159). Exp is only ~10% of wall; the real remaining
// levers are serial-chain cuts:
//  - mx cross-half exchange via permlane32_swap (VALU ~4cyc) replacing __shfl_xor
//    (ds_bpermute ~50-120cyc) on the per-tile critical chain QK->max->gate->exp.
//  - P-pack (pk2+pl32) and the 4 accL ones-MFMAs moved BEFORE B2 (depend only on st);
//    post-B2 region is now pure {8 ds_read_b128 + 8 accO MFMA} -> waves fire MFMAs
//    immediately after the barrier.
// Guards: WRITE_SIZE 25344 KB (no spill); VGPR <= ~96; absmax 0.03125.
// Carried: R12 fused subtract (st init=-m_run) + defer-max THR=8 + ones-MFMA accL +
// epilogue l from accL; R11 NSPLIT=3 zero-tail grid (768 = 3/CU), same-XCD sharers,
// merge3; R8 (256,3), lgkmcnt-only raw barriers (no vmcnt drain), 2-barrier tile,
// V-stage+prefetch under QK, ternary max3 reduce, setprio, register prefetch,
// single-fp16 Q, permlane32_swap P exchange, conflict-free V^T staging, dbuf LDS,
// fp16 MFMA 32x32x16 S^T formulation.

#define NBATCH 32
#define SQL 1024
#define SKVL 8192
#define DH 64
#define BM 128                 // q rows per block (4 waves x 32)
#define BN 64                  // kv rows per tile
#define KSTR 72                // K lds row stride in halfs
#define VSTR 72                // V^T lds row stride in halfs
#define NSPL 3                 // splits per (batch,qb): grid 768 = 3 blocks/CU exactly
#define RESCALE_THR 8.0f       // defer-max threshold (fp16 P <= 2^8)

typedef _Float16 half8 __attribute__((ext_vector_type(8)));
typedef __fp16 fp16x2 __attribute__((ext_vector_type(2)));
typedef float floatx16 __attribute__((ext_vector_type(16)));
typedef float floatx4 __attribute__((ext_vector_type(4)));
typedef unsigned int uint4v __attribute__((ext_vector_type(4)));
typedef unsigned int uint2v __attribute__((ext_vector_type(2)));

union F8U { uint4v u; half8 h; };

#if __has_builtin(__builtin_amdgcn_exp2f)
#define EXP2F(x) __builtin_amdgcn_exp2f(x)
#else
#define EXP2F(x) exp2f(x)
#endif

// __syncthreads minus the vmcnt drain: wait own LDS ops, barrier, fence reordering.
#define WGBAR() do {                                        \
    asm volatile("s_waitcnt lgkmcnt(0)" ::: "memory");      \
    __builtin_amdgcn_s_barrier();                           \
    asm volatile("" ::: "memory");                          \
  } while (0)

static __device__ __forceinline__ unsigned pk2(float a, float b) {
#if __has_builtin(__builtin_amdgcn_cvt_pkrtz)
  fp16x2 h = __builtin_amdgcn_cvt_pkrtz(a, b);
  return __builtin_bit_cast(unsigned, h);
#else
  union { _Float16 h[2]; unsigned u; } r;
  r.h[0] = (_Float16)a; r.h[1] = (_Float16)b; return r.u;
#endif
}

#if __has_builtin(__builtin_amdgcn_permlane32_swap)
#define HAVE_PL32 1
// a' = [a.lo | b.lo], b' = [a.hi | b.hi]  (one VALU instr, both results)
static __device__ __forceinline__ void pl32(unsigned& a, unsigned& b) {
  uint2v r = __builtin_amdgcn_permlane32_swap(a, b, false, false);
  a = r[0]; b = r[1];
}
// value from the partner lane (lane ^ 32), pure VALU (no LDS round-trip)
static __device__ __forceinline__ float xhalf_f32(float x, int hb) {
  unsigned mu = __builtin_bit_cast(unsigned, x);
  uint2v rr = __builtin_amdgcn_permlane32_swap(mu, mu, false, false);
  return __builtin_bit_cast(float, hb ? rr[0] : rr[1]);
}
#else
#define HAVE_PL32 0
#endif

template<int NSPLIT>
__global__ __launch_bounds__(256, 3)
void ring_attn(const float* __restrict__ q, const float* __restrict__ k,
               const float* __restrict__ v, float* __restrict__ out,
               float* __restrict__ pO, float* __restrict__ pM, float* __restrict__ pL)
{
  constexpr int TT = SKVL / BN;            // 128 kv tiles total
  __shared__ _Float16 Kl[2][BN * KSTR];
  __shared__ _Float16 Vt[2][DH * VSTR];

  const int tid  = threadIdx.x;
  const int lane = tid & 63;
  const int wv   = tid >> 6;
  const int l31  = lane & 31;
  const int hb   = lane >> 5;
  const int b8   = hb * 8;

  int split, batch, qb;
  if (NSPLIT == 3) {                 // bi = qb*96 + batch*3 + split, grid 768
    split = blockIdx.x % 3;          // sharers of a K/V slice: bid stride 96 == same XCD
    batch = (blockIdx.x / 3) & 31;
    qb    = blockIdx.x / 96;         // 0..7
  } else {
    split = 0;
    batch = blockIdx.x & 31;
    qb    = blockIdx.x >> 5;
  }
  const int t0 = (split * TT) / NSPLIT;
  const int t1 = ((split + 1) * TT) / NSPLIT;

  const float* kp = k + (size_t)batch * SKVL * DH;
  const float* vp = v + (size_t)batch * SKVL * DH;

  // ---- Q: scale by log2(e), round to fp16 (B-operand frags: n=q=l31, k=d) ----
  const float* qp = q + ((size_t)batch * SQL + qb * BM + wv * 32 + l31) * DH;
  half8 qf[4];
#pragma unroll
  for (int kt = 0; kt < 4; ++kt) {
    float4 a = *(const float4*)(qp + kt * 16 + b8);
    float4 c = *(const float4*)(qp + kt * 16 + b8 + 4);
    float xs[8] = {a.x, a.y, a.z, a.w, c.x, c.y, c.z, c.w};
#pragma unroll
    for (int j = 0; j < 8; ++j)
      qf[kt][j] = (_Float16)(xs[j] * 1.44269504088896340736f);
  }

  // all-ones B operand for the row-sum (l) MFMA
  half8 ones;
#pragma unroll
  for (int j = 0; j < 8; ++j) ones[j] = (_Float16)1.0f;

  // K staging: thread -> row krt(+16*it), cols kc..kc+3 (fp32)
  const int krt = tid >> 4;
  const int kc  = (tid & 15) * 4;
  // V staging (n-major, conflict-free): thread -> rows vnr,vnr+1, cols vcg..vcg+7
  const int vnr = 2 * (tid & 31);
  const int vcg = 8 * (tid >> 5);

  float4 gk[4], ga0, ga1, gb0, gb1;
  {
    const float* kt_ = kp + (size_t)t0 * BN * DH;
    const float* vt_ = vp + (size_t)t0 * BN * DH;
#pragma unroll
    for (int it = 0; it < 4; ++it)
      gk[it] = *(const float4*)(kt_ + (size_t)(krt + it * 16) * DH + kc);
    ga0 = *(const float4*)(vt_ + (size_t)vnr * DH + vcg);
    ga1 = *(const float4*)(vt_ + (size_t)vnr * DH + vcg + 4);
    gb0 = *(const float4*)(vt_ + (size_t)(vnr + 1) * DH + vcg);
    gb1 = *(const float4*)(vt_ + (size_t)(vnr + 1) * DH + vcg + 4);
  }

  floatx16 accO[2], accL;
#pragma unroll
  for (int i = 0; i < 2; ++i)
#pragma unroll
    for (int r = 0; r < 16; ++r) accO[i][r] = 0.f;
#pragma unroll
  for (int r = 0; r < 16; ++r) accL[r] = 0.f;
  float m_run = 0.f;               // deferred running max (lane = q-row l31)

  int buf = 0;
  for (int tile = t0; tile < t1; ++tile) {
    _Float16* Kb = Kl[buf];
    _Float16* Vb = Vt[buf];

    // ---- stage K regs -> LDS[buf] ----
#pragma unroll
    for (int it = 0; it < 4; ++it) {
      uint2 w2 = make_uint2(pk2(gk[it].x, gk[it].y), pk2(gk[it].z, gk[it].w));
      *(uint2*)&Kb[(krt + it * 16) * KSTR + kc] = w2;
    }
    WGBAR();                         // B1: K visible; V loads still in flight

    // ---- stage V regs -> LDS[buf] (overlaps QK below) ----
    {
      float av[8] = {ga0.x, ga0.y, ga0.z, ga0.w, ga1.x, ga1.y, ga1.z, ga1.w};
      float bv[8] = {gb0.x, gb0.y, gb0.z, gb0.w, gb1.x, gb1.y, gb1.z, gb1.w};
#pragma unroll
      for (int i = 0; i < 8; ++i)
        *(unsigned*)&Vb[(vcg + i) * VSTR + vnr] = pk2(av[i], bv[i]);
    }

    // ---- issue next tile's loads ----
    if (tile + 1 < t1) {
      const float* kn = kp + (size_t)(tile + 1) * BN * DH;
      const float* vn = vp + (size_t)(tile + 1) * BN * DH;
#pragma unroll
      for (int it = 0; it < 4; ++it)
        gk[it] = *(const float4*)(kn + (size_t)(krt + it * 16) * DH + kc);
      ga0 = *(const float4*)(vn + (size_t)vnr * DH + vcg);
      ga1 = *(const float4*)(vn + (size_t)vnr * DH + vcg + 4);
      gb0 = *(const float4*)(vn + (size_t)(vnr + 1) * DH + vcg);
      gb1 = *(const float4*)(vn + (size_t)(vnr + 1) * DH + vcg + 4);
    }

    // ---- S' = K_tile · Q^T - m_run  (subtract fused via C-init) ----
    const float negm = -m_run;
    floatx16 st[2];
#pragma unroll
    for (int t = 0; t < 2; ++t)
#pragma unroll
      for (int r = 0; r < 16; ++r) st[t][r] = negm;
    __builtin_amdgcn_s_setprio(1);
#pragma unroll
    for (int kt = 0; kt < 4; ++kt) {
#pragma unroll
      for (int t = 0; t < 2; ++t) {
        half8 kf = *(const half8*)&Kb[(t * 32 + l31) * KSTR + kt * 16 + b8];
        st[t] = __builtin_amdgcn_mfma_f32_32x32x16_f16(kf, qf[kt], st[t], 0, 0, 0);
      }
    }
    __builtin_amdgcn_s_setprio(0);

    // ---- deferred online softmax: max check only; rare rescale path ----
    float mx;
    {
      float a[16];
#pragma unroll
      for (int r = 0; r < 16; ++r) a[r] = fmaxf(st[0][r], st[1][r]);
      float c0 = fmaxf(fmaxf(a[0],  a[1]),  fmaxf(a[2],  a[3]));
      float c1 = fmaxf(fmaxf(a[4],  a[5]),  fmaxf(a[6],  a[7]));
      float c2 = fmaxf(fmaxf(a[8],  a[9]),  fmaxf(a[10], a[11]));
      float c3 = fmaxf(fmaxf(a[12], a[13]), fmaxf(a[14], a[15]));
      mx = fmaxf(fmaxf(c0, c1), fmaxf(c2, c3));
    }
#if HAVE_PL32
    mx = fmaxf(mx, xhalf_f32(mx, hb));        // cross-half via VALU permlane
#else
    mx = fmaxf(mx, __shfl_xor(mx, 32, 64));   // cross-half: full row max
#endif

    if (__any(mx > RESCALE_THR)) {            // rare: max grew meaningfully
      float d  = fmaxf(mx, 0.f);
      m_run += d;
      float al = EXP2F(-d);
#pragma unroll
      for (int t = 0; t < 2; ++t)
#pragma unroll
        for (int r = 0; r < 16; ++r) st[t][r] -= d;
#pragma unroll
      for (int r = 0; r < 16; ++r) {
        int row = (r & 3) + 8 * (r >> 2) + 4 * hb;
        float ar = __shfl(al, row, 64);
        accO[0][r] *= ar;
        accO[1][r] *= ar;
        accL[r]    *= ar;
      }
    }

    // ---- P = exp2(st) (quarter-rate trans; proven cheaper than pk tricks) ----
#pragma unroll
    for (int t = 0; t < 2; ++t)
#pragma unroll
      for (int r = 0; r < 16; ++r)
        st[t][r] = EXP2F(st[t][r]);

    // ---- pack P -> fp16 A-layout + accL ones-MFMA, all BEFORE B2 (no Vb dep) ----
    F8U fe2[2], fo2[2];
#pragma unroll
    for (int t = 0; t < 2; ++t) {
      unsigned P01 = pk2(st[t][0],  st[t][1]);
      unsigned P23 = pk2(st[t][2],  st[t][3]);
      unsigned P45 = pk2(st[t][4],  st[t][5]);
      unsigned P67 = pk2(st[t][6],  st[t][7]);
      unsigned P89 = pk2(st[t][8],  st[t][9]);
      unsigned PAB = pk2(st[t][10], st[t][11]);
      unsigned PCD = pk2(st[t][12], st[t][13]);
      unsigned PEF = pk2(st[t][14], st[t][15]);
#if HAVE_PL32
      pl32(P01, P45); fe2[t].u[0] = P01; fe2[t].u[2] = P45;
      pl32(P23, P67); fe2[t].u[1] = P23; fe2[t].u[3] = P67;
      pl32(P89, PCD); fo2[t].u[0] = P89; fo2[t].u[2] = PCD;
      pl32(PAB, PEF); fo2[t].u[1] = PAB; fo2[t].u[3] = PEF;
#else
      unsigned x01 = __shfl_xor(P01, 32, 64), x23 = __shfl_xor(P23, 32, 64);
      unsigned x45 = __shfl_xor(P45, 32, 64), x67 = __shfl_xor(P67, 32, 64);
      unsigned x89 = __shfl_xor(P89, 32, 64), xAB = __shfl_xor(PAB, 32, 64);
      unsigned xCD = __shfl_xor(PCD, 32, 64), xEF = __shfl_xor(PEF, 32, 64);
      fe2[t].u = uint4v{hb ? x45 : P01, hb ? x67 : P23, hb ? P45 : x01, hb ? P67 : x23};
      fo2[t].u = uint4v{hb ? xCD : P89, hb ? xEF : PAB, hb ? PCD : x89, hb ? PEF : xAB};
#endif
      accL = __builtin_amdgcn_mfma_f32_32x32x16_f16(fe2[t].h, ones, accL, 0, 0, 0);
      accL = __builtin_amdgcn_mfma_f32_32x32x16_f16(fo2[t].h, ones, accL, 0, 0, 0);
    }

    WGBAR();                         // B2: V^T visible; QK reads of Kb drained

    // ---- P·V: pure {ds_read + MFMA} post-barrier ----
    __builtin_amdgcn_s_setprio(1);
#pragma unroll
    for (int t = 0; t < 2; ++t) {
#pragma unroll
      for (int ds = 0; ds < 2; ++ds) {
        half8 vf0 = *(const half8*)&Vb[(ds * 32 + l31) * VSTR + (2 * t) * 16 + b8];
        accO[ds] = __builtin_amdgcn_mfma_f32_32x32x16_f16(fe2[t].h, vf0, accO[ds], 0, 0, 0);
        half8 vf1 = *(const half8*)&Vb[(ds * 32 + l31) * VSTR + (2 * t + 1) * 16 + b8];
        accO[ds] = __builtin_amdgcn_mfma_f32_32x32x16_f16(fo2[t].h, vf1, accO[ds], 0, 0, 0);
      }
    }
    __builtin_amdgcn_s_setprio(0);
    buf ^= 1;
  }

  const int rowbase = batch * SQL + qb * BM + wv * 32;
  if (NSPLIT == 1) {
    float* op = out + (size_t)rowbase * DH;
#pragma unroll
    for (int r = 0; r < 16; ++r) {
      int row = (r & 3) + 8 * (r >> 2) + 4 * hb;
      float lr = 1.0f / accL[r];              // all lanes hold row sums
      op[(size_t)row * DH + l31]      = accO[0][r] * lr;
      op[(size_t)row * DH + 32 + l31] = accO[1][r] * lr;
    }
  } else {
    // unnormalized partials + (m,l) per q-row
    float* po = pO + ((size_t)split * NBATCH * SQL + rowbase) * DH;
#pragma unroll
    for (int r = 0; r < 16; ++r) {
      int row = (r & 3) + 8 * (r >> 2) + 4 * hb;
      po[(size_t)row * DH + l31]      = accO[0][r];
      po[(size_t)row * DH + 32 + l31] = accO[1][r];
    }
    if (hb == 0)
      pM[(size_t)split * NBATCH * SQL + rowbase + l31] = m_run;
    if (l31 == 0) {                           // lanes 0 and 32 cover all 32 rows
#pragma unroll
      for (int r = 0; r < 16; ++r) {
        int row = (r & 3) + 8 * (r >> 2) + 4 * hb;
        pL[(size_t)split * NBATCH * SQL + rowbase + row] = accL[r];
      }
    }
  }
}

__global__ __launch_bounds__(256)
void merge3(const float* __restrict__ pO, const float* __restrict__ pM,
            const float* __restrict__ pL, float* __restrict__ out)
{
  const int i4   = blockIdx.x * 256 + threadIdx.x;    // float4 index
  const int rowg = i4 >> 4;                           // (i4*4)>>6
  const size_t PLANE4 = (size_t)NBATCH * SQL * DH / 4;  // 524288
  const int    RPL    = NBATCH * SQL;                   // 32768
  float m0 = pM[rowg], m1 = pM[RPL + rowg], m2 = pM[2 * RPL + rowg];
  float mx = fmaxf(fmaxf(m0, m1), m2);
  float w0 = EXP2F(m0 - mx), w1 = EXP2F(m1 - mx), w2 = EXP2F(m2 - mx);
  float l = w0 * pL[rowg] + w1 * pL[RPL + rowg] + w2 * pL[2 * RPL + rowg];
  float li = 1.0f / l;
  const floatx4* p0 = (const floatx4*)pO;
  floatx4 o0 = p0[i4], o1 = p0[PLANE4 + i4], o2 = p0[2 * PLANE4 + i4];
  floatx4 o;
#pragma unroll
  for (int j = 0; j < 4; ++j)
    o[j] = (w0 * o0[j] + w1 * o1[j] + w2 * o2[j]) * li;
  ((floatx4*)out)[i4] = o;
}

extern "C" void kernel_launch(void* const* d_in, const int* in_sizes, int n_in,
                              void* d_out, int out_size, void* d_ws, size_t ws_size,
                              hipStream_t stream) {
  (void)in_sizes; (void)n_in; (void)out_size;
  const float* q = (const float*)d_in[0];
  const float* k = (const float*)d_in[1];
  const float* v = (const float*)d_in[2];
  float* out = (float*)d_out;

  const size_t PLANE = (size_t)NBATCH * SQL * DH;              // floats per split plane
  const size_t RPL   = (size_t)NBATCH * SQL;                   // rows per split
  const size_t need  = (3 * PLANE + 6 * RPL) * sizeof(float);  // ~26 MB

  if (ws_size >= need) {
    float* pO = (float*)d_ws;
    float* pM = pO + 3 * PLANE;
    float* pL = pM + 3 * RPL;
    ring_attn<NSPL><<<dim3(768), dim3(256), 0, stream>>>(q, k, v, nullptr, pO, pM, pL);
    merge3<<<dim3((NBATCH * SQL * DH) / 1024), dim3(256), 0, stream>>>(pO, pM, pL, out);
  } else {
    ring_attn<1><<<dim3(256), dim3(256), 0, stream>>>(q, k, v, out, nullptr, nullptr, nullptr);
  }
}